// Round 7
// baseline (466.561 us; speedup 1.0000x reference)
//
#include <hip/hip_runtime.h>
#include <stddef.h>

// Problem constants (match reference setup_inputs)
constexpr int N_NODES = 200000;
constexpr int N_EDGES = 200000;
constexpr int N_GRAPHS = 128;
constexpr int IN_F = 256;
constexpr int HID_F = 128;
constexpr int OUT_F = 128;
constexpr int OUT_W = OUT_F + HID_F; // 256 output cols per graph
constexpr int SCAN_NB = (N_NODES + 1023) / 1024; // 196 blocks

typedef __attribute__((ext_vector_type(8))) short short8;   // bf16x8 MFMA A/B frag
typedef __attribute__((ext_vector_type(4))) float float4v;  // fp32x4 MFMA C/D frag

__device__ __forceinline__ short f2bf(float f) {
    union { float f; unsigned u; } v; v.f = f;
    unsigned r = v.u + 0x7fffu + ((v.u >> 16) & 1u);  // RNE
    return (short)(r >> 16);
}
__device__ __forceinline__ float bf2f(unsigned short s) {
    union { unsigned u; float f; } v; v.u = ((unsigned)s) << 16;
    return v.f;
}

// ---------------- small utility kernels ----------------

// in-degree counts (int) per edge
__global__ void edge_prep_kernel(const int* __restrict__ dst, int* __restrict__ cntin, int E) {
    int e = blockIdx.x * blockDim.x + threadIdx.x;
    if (e < E) atomicAdd(&cntin[dst[e]], 1);
}

// ---- hierarchical exclusive scan (R4 post-mortem: single-block scan was 465us) ----

__global__ __launch_bounds__(1024) void scan_reduce_kernel(const int* __restrict__ cnt,
                                                           int* __restrict__ partial, int n) {
    __shared__ int sm[1024];
    int t = threadIdx.x;
    int i = blockIdx.x * 1024 + t;
    sm[t] = (i < n) ? cnt[i] : 0;
    __syncthreads();
    for (int ofs = 512; ofs > 0; ofs >>= 1) {
        if (t < ofs) sm[t] += sm[t + ofs];
        __syncthreads();
    }
    if (t == 0) partial[blockIdx.x] = sm[0];
}

__global__ void scan_base_kernel(int* __restrict__ partial, int nb) {
    __shared__ int sm[256];
    int t = threadIdx.x;
    sm[t] = (t < nb) ? partial[t] : 0;
    __syncthreads();
    for (int ofs = 1; ofs < 256; ofs <<= 1) {
        int v = (t >= ofs) ? sm[t - ofs] : 0;
        __syncthreads();
        sm[t] += v;
        __syncthreads();
    }
    if (t < nb) partial[t] = (t == 0) ? 0 : sm[t - 1];
}

// phase 3 + fused dinv[i] = rsqrt(1+indeg)
__global__ __launch_bounds__(1024) void scan_final_kernel(const int* __restrict__ cnt,
                                                          const int* __restrict__ partial,
                                                          int* __restrict__ rp,
                                                          int* __restrict__ cur,
                                                          float* __restrict__ dinv, int n) {
    __shared__ int sm[1024];
    int t = threadIdx.x;
    int i = blockIdx.x * 1024 + t;
    int v = (i < n) ? cnt[i] : 0;
    sm[t] = v;
    __syncthreads();
    for (int ofs = 1; ofs < 1024; ofs <<= 1) {
        int u = (t >= ofs) ? sm[t - ofs] : 0;
        __syncthreads();
        sm[t] += u;
        __syncthreads();
    }
    int base = partial[blockIdx.x];
    if (i < n) {
        int ex = base + sm[t] - v; // exclusive
        rp[i] = ex;
        cur[i] = ex;
        dinv[i] = rsqrtf(1.0f + (float)v);
        if (i == n - 1) rp[n] = ex + v;
    }
}

// adj[pos] = src[e], bucketed by dst (CSR-by-dst). Order within a row arbitrary.
__global__ void bucket_kernel(const int* __restrict__ src, const int* __restrict__ dst,
                              int* __restrict__ cur, int* __restrict__ adj, int E) {
    int e = blockIdx.x * blockDim.x + threadIdx.x;
    if (e < E) {
        int pos = atomicAdd(&cur[dst[e]], 1);
        adj[pos] = src[e];
    }
}

// batch is SORTED: segment bounds by binary search (R1 post-mortem)
__global__ void bounds_kernel(const int* __restrict__ batch, int* __restrict__ start,
                              int* __restrict__ cnt, int n, int G) {
    __shared__ int s_start[N_GRAPHS + 1];
    int g = threadIdx.x;
    if (g < G) {
        int lo = 0, hi = n;
        while (lo < hi) {
            int mid = (lo + hi) >> 1;
            if (batch[mid] < g) lo = mid + 1; else hi = mid;
        }
        s_start[g] = lo;
        if (g == 0) s_start[G] = n;
    }
    __syncthreads();
    if (g < G) {
        start[g] = s_start[g];
        cnt[g] = s_start[g + 1] - s_start[g];
    }
}

// Both weight pre-transposes in one launch: Bt[n*K + k] = bf16(W[k*128 + n]).
__global__ void transpose_w_kernel(const float* __restrict__ W1, const float* __restrict__ W2,
                                   short* __restrict__ Bt1, short* __restrict__ Bt2) {
    int k = blockIdx.x;
    int n = threadIdx.x;
    if (k < IN_F) {
        Bt1[(size_t)n * IN_F + k] = f2bf(W1[(size_t)k * 128 + n]);
    } else {
        int kk = k - IN_F;
        Bt2[(size_t)n * HID_F + kk] = f2bf(W2[(size_t)kk * 128 + n]);
    }
}

// rootlin[g,f] = sum_k relu(x[root_index[g],k]) * W2[(HID_F+k)*OUT_F + f]
__global__ void rootlin_kernel(const float* __restrict__ x, const int* __restrict__ root_index,
                               const float* __restrict__ W2, float* __restrict__ rootlin)
{
    int g = blockIdx.x;
    int f = threadIdx.x; // OUT_F threads
    int r = root_index[g];
    const float* xr = x + (size_t)r * IN_F;
    float acc = 0.f;
    for (int k = 0; k < IN_F; ++k) {
        float xv = fmaxf(xr[k], 0.f);
        acc += xv * W2[(size_t)(HID_F + k) * OUT_F + f];
    }
    rootlin[(size_t)g * OUT_F + f] = acc;
}

// ---------------- bf16 MFMA GEMM, 128x128 tile ----------------
// R7: 64-row tile staged the full B per block (3125x redundant B-LDS traffic,
// 64 MFMA/wave per barrier); 128-row tile halves blocks, doubles MFMA/barrier.
// out[M,128] = op(A)[M,KTOT] @ B[KTOT,128], epilogue v = dinv[row]*(acc [+ rootlin]),
// stored bf16. GATHER (conv2, KTOT==128): pull-mode conv1 aggregation via CSR.
// N not divisible by 128: clamped loads + guarded stores.
template<int KTOT, bool GATHER, bool ADDROOT>
__global__ __launch_bounds__(256, 2) void mfma_gemm_kernel(
    const void* __restrict__ Ap, const short* __restrict__ Bt,
    unsigned short* __restrict__ outp,
    const float* __restrict__ dinv, const float* __restrict__ bvec,
    const float* __restrict__ rootlin, const int* __restrict__ batch,
    const int* __restrict__ rp, const int* __restrict__ adj)
{
    // stride 136 shorts = 272B (mult of 16B for b128 ops); bank stride 68 dwords
    // == 4 mod 32 -> 2-way conflicts only (free, m136)
    __shared__ __align__(16) short As[128][136];
    __shared__ __align__(16) short Bs[128][136];

    const int tid = threadIdx.x;
    const int wave = tid >> 6;
    const int lane = tid & 63;
    const int quad = lane >> 4;
    const int l16  = lane & 15;
    const int row0 = blockIdx.x * 128;

    float4v acc[2][8];
    #pragma unroll
    for (int rb = 0; rb < 2; ++rb)
        #pragma unroll
        for (int c = 0; c < 8; ++c) acc[rb][c] = (float4v){0.f, 0.f, 0.f, 0.f};

    // B staging: 2 threads/row, 64-short halves
    const int bn = tid >> 1;
    const int bh = (tid & 1) * 64;

    for (int kb = 0; kb < KTOT / 128; ++kb) {
        {
            const short* bp = Bt + (size_t)bn * KTOT + kb * 128 + bh;
            #pragma unroll
            for (int j = 0; j < 8; ++j)
                *(short8*)&Bs[bn][bh + 8 * j] = *(const short8*)(bp + 8 * j);
        }
        if (GATHER) {
            // 2 threads/row: thread covers 64 bf16 cols of its row
            const unsigned short* A = (const unsigned short*)Ap;
            const int trow = row0 + (tid >> 1);
            const int rowc = min(trow, N_NODES - 1);
            const int tcol = (tid & 1) * 64;
            float sum[8][8];
            const unsigned short* hp = A + (size_t)rowc * 128 + tcol;
            #pragma unroll
            for (int j = 0; j < 8; ++j) {
                short8 h = *(const short8*)(hp + 8 * j);
                #pragma unroll
                for (int q = 0; q < 8; ++q) sum[j][q] = bf2f((unsigned short)h[q]);
            }
            int e0 = rp[rowc], e1 = rp[rowc + 1];
            for (int e = e0; e < e1; ++e) {
                const unsigned short* qp = A + (size_t)adj[e] * 128 + tcol;
                #pragma unroll
                for (int j = 0; j < 8; ++j) {
                    short8 h = *(const short8*)(qp + 8 * j);
                    #pragma unroll
                    for (int q = 0; q < 8; ++q) sum[j][q] += bf2f((unsigned short)h[q]);
                }
            }
            float asc = dinv[rowc];
            #pragma unroll
            for (int j = 0; j < 8; ++j) {
                const float* bv = bvec + tcol + 8 * j;
                short8 s;
                #pragma unroll
                for (int q = 0; q < 8; ++q)
                    s[q] = f2bf(fmaxf(asc * sum[j][q] + bv[q], 0.f));
                *(short8*)&As[tid >> 1][tcol + 8 * j] = s;
            }
        } else {
            // fp32 A, half-wave per row: per instruction 2 rows x 512B contiguous
            const float* A = (const float*)Ap;
            const int rbase = wave * 32 + (lane >> 5);   // + 2*i
            const int cf = (lane & 31) * 4;              // float col
            #pragma unroll
            for (int i = 0; i < 16; ++i) {
                int r = rbase + 2 * i;
                int rowc = min(row0 + r, N_NODES - 1);
                float4 f = *(const float4*)(A + (size_t)rowc * KTOT + kb * 128 + cf);
                ushort4 s;
                s.x = (unsigned short)f2bf(f.x);
                s.y = (unsigned short)f2bf(f.y);
                s.z = (unsigned short)f2bf(f.z);
                s.w = (unsigned short)f2bf(f.w);
                *(ushort4*)&As[r][cf] = s;
            }
        }
        __syncthreads();
        #pragma unroll
        for (int ks = 0; ks < 4; ++ks) {
            // A frags: A[m][k=ks*32+quad*8+j] (m89-verified layout), 2 row-blocks/wave
            short8 af0 = *(const short8*)&As[wave * 32 + l16][ks * 32 + quad * 8];
            short8 af1 = *(const short8*)&As[wave * 32 + 16 + l16][ks * 32 + quad * 8];
            #pragma unroll
            for (int c = 0; c < 8; ++c) {
                short8 bf = *(const short8*)&Bs[c * 16 + l16][ks * 32 + quad * 8];
                acc[0][c] = __builtin_amdgcn_mfma_f32_16x16x32_bf16(af0, bf, acc[0][c], 0, 0, 0);
                acc[1][c] = __builtin_amdgcn_mfma_f32_16x16x32_bf16(af1, bf, acc[1][c], 0, 0, 0);
            }
        }
        __syncthreads();
    }

    // epilogue: D[row=quad*4+r][col=c*16+l16] (m89-verified C/D layout); bf16 store
    #pragma unroll
    for (int rb = 0; rb < 2; ++rb) {
        #pragma unroll
        for (int r = 0; r < 4; ++r) {
            int row = row0 + wave * 32 + rb * 16 + quad * 4 + r;
            if (row >= N_NODES) continue;
            float di = dinv[row];
            const float* rl = nullptr;
            if (ADDROOT) rl = rootlin + (size_t)batch[row] * 128;
            #pragma unroll
            for (int c = 0; c < 8; ++c) {
                int col = c * 16 + l16;
                float v = acc[rb][c][r];
                if (ADDROOT) v += rl[col];
                outp[(size_t)row * 128 + col] = (unsigned short)f2bf(v * di);
            }
        }
    }
}

// out[g,0:128]   = (1/n) sum_seg relu(dinv[i]*(hs2[i]+sum_in hs2[adj]) + b2)
// out[g,128:256] = n>0 ? dinv[r]*(hs1[r]+sum_in hs1[adj]) + b1 : 0
// hs1/hs2 bf16. grid (G, chunks) x 128 threads; out pre-zeroed.
__global__ void mean_kernel(const unsigned short* __restrict__ hs2,
                            const unsigned short* __restrict__ hs1,
                            const float* __restrict__ dinv, const float* __restrict__ b1v,
                            const float* __restrict__ b2v, const int* __restrict__ root_index,
                            const int* __restrict__ cnt, const int* __restrict__ start,
                            const int* __restrict__ rp, const int* __restrict__ adj,
                            float* __restrict__ out, int chunks)
{
    int g = blockIdx.x;
    int c = blockIdx.y;
    int f = threadIdx.x; // 128
    int s = start[g], n = cnt[g];
    int per = (n + chunks - 1) / chunks;
    int lo = s + c * per;
    int hi = min(s + n, lo + per);
    float bb = b2v[f];
    float accv = 0.f;
    for (int i = lo; i < hi; ++i) {
        float v = bf2f(hs2[(size_t)i * 128 + f]);
        int e0 = rp[i], e1 = rp[i + 1];
        for (int e = e0; e < e1; ++e)
            v += bf2f(hs2[(size_t)adj[e] * 128 + f]);
        accv += fmaxf(dinv[i] * v + bb, 0.f);
    }
    if (hi > lo)
        atomicAdd(&out[(size_t)g * OUT_W + f], accv / (float)max(n, 1));
    if (c == 0) {
        int r = root_index[g];
        float v = 0.f;
        if (n > 0) {
            v = bf2f(hs1[(size_t)r * 128 + f]);
            int e0 = rp[r], e1 = rp[r + 1];
            for (int e = e0; e < e1; ++e)
                v += bf2f(hs1[(size_t)adj[e] * 128 + f]);
            v = dinv[r] * v + b1v[f];
        }
        out[(size_t)g * OUT_W + HID_F + f] = v;
    }
}

// ---------------- launch ----------------

static inline size_t align_up(size_t x, size_t a) { return (x + a - 1) / a * a; }

extern "C" void kernel_launch(void* const* d_in, const int* in_sizes, int n_in,
                              void* d_out, int out_size, void* d_ws, size_t ws_size,
                              hipStream_t stream) {
    const float* x = (const float*)d_in[0];
    const int* ei = (const int*)d_in[1];
    const int* batch = (const int*)d_in[2];
    const int* root = (const int*)d_in[3];
    const float* W1 = (const float*)d_in[4];
    const float* b1 = (const float*)d_in[5];
    const float* W2 = (const float*)d_in[6];
    const float* b2 = (const float*)d_in[7];
    float* out = (float*)d_out;

    const int* src = ei;
    const int* dst = ei + N_EDGES;

    // workspace carve-up
    char* ws = (char*)d_ws;
    size_t off = 0;
    const size_t NB16 = (size_t)N_NODES * 128 * sizeof(unsigned short); // 51.2 MB

    float* dinv = (float*)(ws + off);    off = align_up(off + (size_t)N_NODES * sizeof(float), 256);
    int* cnt = (int*)(ws + off);         off = align_up(off + N_GRAPHS * sizeof(int), 256);
    int* startv = (int*)(ws + off);      off = align_up(off + N_GRAPHS * sizeof(int), 256);
    float* rootlin = (float*)(ws + off); off = align_up(off + (size_t)N_GRAPHS * OUT_F * sizeof(float), 256);
    short* Bt1 = (short*)(ws + off);     off = align_up(off + (size_t)128 * IN_F * sizeof(short), 256);
    short* Bt2 = (short*)(ws + off);     off = align_up(off + (size_t)128 * HID_F * sizeof(short), 256);
    int* rowptr = (int*)(ws + off);      off = align_up(off + (size_t)(N_NODES + 1) * sizeof(int), 256);
    int* cursor = (int*)(ws + off);      off = align_up(off + (size_t)N_NODES * sizeof(int), 256);
    int* partial = (int*)(ws + off);     off = align_up(off + (size_t)SCAN_NB * sizeof(int), 256);
    int* adj = (int*)(ws + off);         off = align_up(off + (size_t)N_EDGES * sizeof(int), 256);
    unsigned short* hs1 = (unsigned short*)(ws + off); off = align_up(off + NB16, 256);
    unsigned short* hs2 = (unsigned short*)(ws + off); off = align_up(off + NB16, 256);
    (void)ws_size; (void)n_in; (void)in_sizes; (void)out_size;

    // in-degree -> CSR-by-dst via hierarchical scan (+ fused dinv) + bucket
    hipMemsetAsync(cursor, 0, (size_t)N_NODES * sizeof(int), stream);
    edge_prep_kernel<<<(N_EDGES + 255) / 256, 256, 0, stream>>>(dst, cursor, N_EDGES);
    scan_reduce_kernel<<<SCAN_NB, 1024, 0, stream>>>(cursor, partial, N_NODES);
    scan_base_kernel<<<1, 256, 0, stream>>>(partial, SCAN_NB);
    scan_final_kernel<<<SCAN_NB, 1024, 0, stream>>>(cursor, partial, rowptr, cursor, dinv, N_NODES);
    bucket_kernel<<<(N_EDGES + 255) / 256, 256, 0, stream>>>(src, dst, cursor, adj, N_EDGES);
    bounds_kernel<<<1, N_GRAPHS, 0, stream>>>(batch, startv, cnt, N_NODES, N_GRAPHS);

    // weight pre-transposes (one launch) + rootlin from raw x
    transpose_w_kernel<<<IN_F + HID_F, 128, 0, stream>>>(W1, W2, Bt1, Bt2);
    rootlin_kernel<<<N_GRAPHS, OUT_F, 0, stream>>>(x, root, W2, rootlin);

    const int gemm_grid = (N_NODES + 127) / 128;

    // conv1 linear: hs1 = bf16( dinv .* (x @ W1) )
    mfma_gemm_kernel<IN_F, false, false><<<gemm_grid, 256, 0, stream>>>(
        x, Bt1, hs1, dinv, nullptr, nullptr, nullptr, nullptr, nullptr);

    // conv2 linear, pulling conv1 aggregation via CSR in the A-staging:
    // hs2 = bf16( dinv .* ( relu(dinv.*(hs1 + gather) + b1) @ W2[0:128] + rootlin[batch] ) )
    mfma_gemm_kernel<HID_F, true, true><<<gemm_grid, 256, 0, stream>>>(
        hs1, Bt2, hs2, dinv, b1, rootlin, batch, rowptr, adj);

    // fused conv2-aggregation + relu + graph mean + root gather
    hipMemsetAsync(out, 0, (size_t)N_GRAPHS * OUT_W * sizeof(float), stream);
    dim3 mg(N_GRAPHS, 32);
    mean_kernel<<<mg, 128, 0, stream>>>(hs2, hs1, dinv, b1, b2, root, cnt, startv,
                                        rowptr, adj, out, 32);
}